// Round 2
// baseline (559.954 us; speedup 1.0000x reference)
//
#include <hip/hip_runtime.h>
#include <hip/hip_bf16.h>

// Problem constants: B=2, L=4096, D=768, H=12, HS=64, SCALE=0.125
// Inputs x, Wq, Wo are FLOAT32; output is FLOAT32. Internally: bf16 MFMA, fp32 accum.
#define LQ 4096
#define DQ 768
#define NH 12
#define NB 2

typedef __attribute__((ext_vector_type(8))) short short8;
typedef __attribute__((ext_vector_type(4))) float f32x4;

__device__ __forceinline__ short f2bf(float f) {
    union { float f; unsigned u; } v; v.f = f;
    unsigned r = v.u + 0x7FFFu + ((v.u >> 16) & 1u);   // round-to-nearest-even
    return (short)(r >> 16);
}

__device__ __forceinline__ f32x4 mfma16(short8 a, short8 b, f32x4 c) {
    return __builtin_amdgcn_mfma_f32_16x16x32_bf16(a, b, c, 0, 0, 0);
}

// C[M,N] = A[M,K] @ W[N,K]^T, M=8192, N=768, K=768. fp32 accum.
// AF32: A is float32 (convert to bf16 while staging); else A is bf16.
// MODE 0: C = float32 row-major [M,768] (final output, direct fp32 store)
// MODE 1: C = bf16 scattered to Q layout [(b*12+h)][l][hs] (for attention)
template <bool AF32, int MODE>
__global__ __launch_bounds__(256) void gemm_nt(const void* __restrict__ Ap,
                                               const float* __restrict__ W,
                                               void* __restrict__ Cp) {
    __shared__ short As[128 * 40];   // 32 K-elems + 8 pad (breaks bank aliasing)
    __shared__ short Bs[128 * 40];
    const int t = threadIdx.x;
    const int lane = t & 63, w = t >> 6;
    const int lr = lane & 15, qd = lane >> 4;
    const int wr = (w >> 1) * 64, wc = (w & 1) * 64;
    const int m0 = blockIdx.y * 128, n0 = blockIdx.x * 128;

    f32x4 acc[4][4];
#pragma unroll
    for (int i = 0; i < 4; ++i)
#pragma unroll
        for (int j = 0; j < 4; ++j) acc[i][j] = (f32x4){0.f, 0.f, 0.f, 0.f};

    for (int k0 = 0; k0 < DQ; k0 += 32) {
        // stage A-tile: 128 rows x 32 K-elems
        if (AF32) {
            const float* A = (const float*)Ap;
#pragma unroll
            for (int c = t; c < 1024; c += 256) {           // 4 fp32 per chunk
                int row = c >> 3, col = (c & 7) << 2;
                const float4 v = *(const float4*)&A[(size_t)(m0 + row) * DQ + k0 + col];
                short* d = &As[row * 40 + col];
                d[0] = f2bf(v.x); d[1] = f2bf(v.y); d[2] = f2bf(v.z); d[3] = f2bf(v.w);
            }
        } else {
            const short* A = (const short*)Ap;
#pragma unroll
            for (int c = t; c < 512; c += 256) {            // 8 bf16 per chunk
                int row = c >> 2, col = (c & 3) << 3;
                *(short8*)&As[row * 40 + col] =
                    *(const short8*)&A[(size_t)(m0 + row) * DQ + k0 + col];
            }
        }
        // stage W-tile (always fp32 -> bf16)
#pragma unroll
        for (int c = t; c < 1024; c += 256) {
            int row = c >> 3, col = (c & 7) << 2;
            const float4 v = *(const float4*)&W[(size_t)(n0 + row) * DQ + k0 + col];
            short* d = &Bs[row * 40 + col];
            d[0] = f2bf(v.x); d[1] = f2bf(v.y); d[2] = f2bf(v.z); d[3] = f2bf(v.w);
        }
        __syncthreads();
        short8 af[4], bf[4];
#pragma unroll
        for (int i = 0; i < 4; ++i)
            af[i] = *(short8*)&As[(wr + 16 * i + lr) * 40 + qd * 8];
#pragma unroll
        for (int j = 0; j < 4; ++j)
            bf[j] = *(short8*)&Bs[(wc + 16 * j + lr) * 40 + qd * 8];
#pragma unroll
        for (int i = 0; i < 4; ++i)
#pragma unroll
            for (int j = 0; j < 4; ++j)
                acc[i][j] = mfma16(af[i], bf[j], acc[i][j]);
        __syncthreads();
    }

    // epilogue: C/D layout col=lane&15, row=quad*4+reg (m89/m91 verified)
#pragma unroll
    for (int i = 0; i < 4; ++i)
#pragma unroll
        for (int j = 0; j < 4; ++j)
#pragma unroll
            for (int r = 0; r < 4; ++r) {
                int row = m0 + wr + 16 * i + qd * 4 + r;   // global M index (b*4096+l)
                int col = n0 + wc + 16 * j + lr;           // N index (e)
                if (MODE == 0) {
                    ((float*)Cp)[(size_t)row * DQ + col] = acc[i][j][r];
                } else {
                    int b = row >> 12, l = row & 4095;
                    int h = col >> 6, hs = col & 63;
                    ((short*)Cp)[((size_t)((b * NH + h) * LQ + l)) * 64 + hs] =
                        f2bf(acc[i][j][r]);
                }
            }
}

// Flash attention, K = V = Q. Q layout [bh][l][64] bf16. One block per (bh, 64-query tile).
// 4 waves; wave w owns query rows [16w,16w+16). Online softmax state per row in regs.
__global__ __launch_bounds__(256) void attn(const short* __restrict__ Q,
                                            short* __restrict__ O) {
    const int bh = blockIdx.y, qb = blockIdx.x;
    const int t = threadIdx.x;
    const int lane = t & 63, w = t >> 6;
    const int lr = lane & 15, qd = lane >> 4;

    __shared__ short Ks[64 * 72];      // key-block, row-major [key][d], pad to 72
    __shared__ short Vts[64 * 72];     // transposed [d][key], pad to 72
    __shared__ short Ps[4][16 * 72];   // per-wave P round-trip (C-layout -> A-layout)

    const short* Qbh = Q + (size_t)bh * LQ * 64;

    // Q fragments for this wave's 16 rows (A-layout: m=lane&15, k=quad*8+j)
    short8 aq[2];
    const int qrow = qb * 64 + 16 * w + lr;
#pragma unroll
    for (int s = 0; s < 2; ++s)
        aq[s] = *(const short8*)&Qbh[(size_t)qrow * 64 + 32 * s + qd * 8];

    f32x4 oacc[4];
#pragma unroll
    for (int t2 = 0; t2 < 4; ++t2) oacc[t2] = (f32x4){0.f, 0.f, 0.f, 0.f};
    float m_st[4], l_st[4];
#pragma unroll
    for (int r = 0; r < 4; ++r) { m_st[r] = -1e30f; l_st[r] = 0.f; }

    for (int kb = 0; kb < LQ / 64; ++kb) {
        const short* Kb = Qbh + (size_t)kb * 64 * 64;   // contiguous 8KB block
        // stage: 64 rows x 64 elems, 512 16B chunks, 2 per thread, coalesced
#pragma unroll
        for (int c = t; c < 512; c += 256) {
            int row = c >> 3, col = (c & 7) << 3;
            *(short8*)&Ks[row * 72 + col] = *(const short8*)&Kb[row * 64 + col];
        }
        __syncthreads();

        // build transposed copy for PV B-frags
        {
            int dim = t & 63, kk0 = (t >> 6) * 16;
#pragma unroll
            for (int kk = 0; kk < 16; ++kk)
                Vts[dim * 72 + kk0 + kk] = Ks[(kk0 + kk) * 72 + dim];
        }

        // S = Q * K^T : 4 col-tiles of 16 keys, 2 k-steps over d
        f32x4 sacc[4];
#pragma unroll
        for (int t4 = 0; t4 < 4; ++t4) {
            sacc[t4] = (f32x4){0.f, 0.f, 0.f, 0.f};
#pragma unroll
            for (int s = 0; s < 2; ++s) {
                short8 kf = *(short8*)&Ks[(16 * t4 + lr) * 72 + 32 * s + qd * 8];
                sacc[t4] = mfma16(aq[s], kf, sacc[t4]);
            }
        }

        // online softmax (rows replicated across the 16-lane group; xor 1/2/4/8 stays in-group)
        float s[4][4];
#pragma unroll
        for (int t4 = 0; t4 < 4; ++t4)
#pragma unroll
            for (int r = 0; r < 4; ++r) s[t4][r] = sacc[t4][r] * 0.125f;

        float alpha[4];
#pragma unroll
        for (int r = 0; r < 4; ++r) {
            float m = fmaxf(fmaxf(s[0][r], s[1][r]), fmaxf(s[2][r], s[3][r]));
            m = fmaxf(m, __shfl_xor(m, 1));
            m = fmaxf(m, __shfl_xor(m, 2));
            m = fmaxf(m, __shfl_xor(m, 4));
            m = fmaxf(m, __shfl_xor(m, 8));
            float mn = fmaxf(m_st[r], m);
            alpha[r] = __expf(m_st[r] - mn);
            m_st[r] = mn;
            float l = 0.f;
#pragma unroll
            for (int t4 = 0; t4 < 4; ++t4) {
                s[t4][r] = __expf(s[t4][r] - mn);
                l += s[t4][r];
            }
            l += __shfl_xor(l, 1);
            l += __shfl_xor(l, 2);
            l += __shfl_xor(l, 4);
            l += __shfl_xor(l, 8);
            l_st[r] = l_st[r] * alpha[r] + l;
        }
#pragma unroll
        for (int t2 = 0; t2 < 4; ++t2)
#pragma unroll
            for (int r = 0; r < 4; ++r) oacc[t2][r] *= alpha[r];

        // P: C-layout regs -> LDS (row = quad*4+r, col = 16*t4+lane&15)
#pragma unroll
        for (int t4 = 0; t4 < 4; ++t4)
#pragma unroll
            for (int r = 0; r < 4; ++r)
                Ps[w][(qd * 4 + r) * 72 + 16 * t4 + lr] = f2bf(s[t4][r]);
        __syncthreads();   // covers P write->read, Vts write->read, Ks reads done

        // O += P * V : A-frag from Ps (m=lane&15, k=quad*8+j), B-frag b128 from Vts
#pragma unroll
        for (int ks = 0; ks < 2; ++ks) {
            short8 pa = *(short8*)&Ps[w][lr * 72 + 32 * ks + qd * 8];
#pragma unroll
            for (int t2 = 0; t2 < 4; ++t2) {
                short8 vb = *(short8*)&Vts[(16 * t2 + lr) * 72 + 32 * ks + qd * 8];
                oacc[t2] = mfma16(pa, vb, oacc[t2]);
            }
        }
        __syncthreads();   // protect Ks/Vts/Ps before next iteration's staging
    }

    // epilogue: O[l][h*64+d] in [b,l,768] layout (bf16) for the output projection
    const int b = bh / NH, h = bh % NH;
    float inv[4];
#pragma unroll
    for (int r = 0; r < 4; ++r) inv[r] = 1.0f / l_st[r];
#pragma unroll
    for (int t2 = 0; t2 < 4; ++t2)
#pragma unroll
        for (int r = 0; r < 4; ++r) {
            int l = qb * 64 + 16 * w + qd * 4 + r;
            int e = h * 64 + 16 * t2 + lr;
            O[((size_t)(b * LQ + l)) * DQ + e] = f2bf(oacc[t2][r] * inv[r]);
        }
}

extern "C" void kernel_launch(void* const* d_in, const int* in_sizes, int n_in,
                              void* d_out, int out_size, void* d_ws, size_t ws_size,
                              hipStream_t stream) {
    (void)in_sizes; (void)n_in; (void)out_size; (void)ws_size;
    const float* x  = (const float*)d_in[0];   // fp32 [2,4096,768]
    const float* Wq = (const float*)d_in[1];   // fp32 [768,768]
    const float* Wo = (const float*)d_in[2];   // fp32 [768,768]
    float* out = (float*)d_out;                // fp32 [2,4096,768]

    short* Qws = (short*)d_ws;                               // [24][4096][64] bf16
    short* Ows = Qws + (size_t)NB * NH * LQ * 64;            // [2][4096][768] bf16

    // 1) Q = bf16(x) @ bf16(Wq)^T, scattered to [bh][l][hs] (bf16)
    gemm_nt<true, 1><<<dim3(DQ / 128, (NB * LQ) / 128), 256, 0, stream>>>(x, Wq, Qws);
    // 2) flash attention with K=V=Q (bf16 in/out, fp32 state)
    attn<<<dim3(LQ / 64, NB * NH), 256, 0, stream>>>(Qws, Ows);
    // 3) out = O @ bf16(Wo)^T, fp32 store
    gemm_nt<false, 0><<<dim3(DQ / 128, (NB * LQ) / 128), 256, 0, stream>>>(Ows, Wo, out);
}